// Round 1
// baseline (399.680 us; speedup 1.0000x reference)
//
#include <hip/hip_runtime.h>
#include <hip/hip_bf16.h>
#include <stdint.h>

// Problem constants
// B=8, N=4096, C=512, K=V=512, H=8, hk=hv=64, M = B*N = 32768

typedef __attribute__((ext_vector_type(8))) short short8;
typedef __attribute__((ext_vector_type(4))) float f32x4;
typedef __attribute__((ext_vector_type(4))) unsigned short us4;

__device__ __forceinline__ unsigned short f2bf(float f) {
  union { float f; unsigned u; } v; v.f = f;
  unsigned r = v.u + 0x7FFFu + ((v.u >> 16) & 1u);  // RNE
  return (unsigned short)(r >> 16);
}
__device__ __forceinline__ float bf2f(unsigned short u) {
  union { unsigned u; float f; } v; v.u = ((unsigned)u) << 16;
  return v.f;
}

// ---------------------------------------------------------------------------
// Transpose + bf16-convert the 4 weight matrices: Wt[w][out][in] = W[in][out]
__global__ void prep_w(const float* __restrict__ Wk, const float* __restrict__ Wq,
                       const float* __restrict__ Wv, const float* __restrict__ Wr,
                       unsigned short* __restrict__ Wt) {
  __shared__ float tile[64][65];
  const int t = threadIdx.x;
  const int bx = blockIdx.x, by = blockIdx.y, w = blockIdx.z;
  const float* W = (w == 0) ? Wk : (w == 1) ? Wq : (w == 2) ? Wv : Wr;
  unsigned short* O = Wt + (size_t)w * 512 * 512;
#pragma unroll
  for (int p = 0; p < 16; ++p) {
    int idx = p * 256 + t; int r = idx >> 6, c = idx & 63;
    tile[r][c] = W[(size_t)(by * 64 + r) * 512 + bx * 64 + c];
  }
  __syncthreads();
#pragma unroll
  for (int p = 0; p < 16; ++p) {
    int idx = p * 256 + t; int r = idx >> 6, c = idx & 63;
    O[(size_t)(bx * 64 + r) * 512 + by * 64 + c] = f2bf(tile[c][r]);
  }
}

// ---------------------------------------------------------------------------
// Projection GEMM: [32768 x 512] = A(fp32) @ W(bf16, B^T layout) + bias
// MODE 0: A = x + y, epilogue exp(), TRANSPOSED out (KeT[b][k][tok], bf16)
// MODE 1: A = y,      plain,          row-major out (Qp[tok][ch], bf16)
// MODE 2: A = x,      plain,          TRANSPOSED out (VT[b][v][tok], bf16)
template <int MODE>
__global__ void gemm_proj(const float* __restrict__ A0, const float* __restrict__ A1,
                          const unsigned short* __restrict__ Bt, const float* __restrict__ bias,
                          unsigned short* __restrict__ Out) {
  __shared__ __align__(16) unsigned short As[128][64];
  __shared__ __align__(16) unsigned short Bs[128][64];
  const int t = threadIdx.x;
  const int l = t & 63, w = t >> 6;
  const int lr = l & 15, lg = l >> 4;
  const int wr = w >> 1, wc = w & 1;
  const int tn = blockIdx.x, tm = blockIdx.y;  // tn fast: same-tm blocks adjacent -> L2 reuse of A

  f32x4 acc[4][4] = {};
  const int r = t >> 1, half = t & 1;

  for (int kt = 0; kt < 8; ++kt) {
    if (kt) __syncthreads();
    // ---- stage A: fp32 global -> bf16 LDS (reg path) ----
    {
      const float* a0 = A0 + (size_t)(tm * 128 + r) * 512 + kt * 64 + half * 32;
      float4 x0[4], x1[4];
#pragma unroll
      for (int it = 0; it < 4; ++it) {
        x0[it] = *(const float4*)(a0 + it * 8);
        x1[it] = *(const float4*)(a0 + it * 8 + 4);
      }
      if (MODE == 0) {
        const float* a1 = A1 + (size_t)(tm * 128 + r) * 512 + kt * 64 + half * 32;
#pragma unroll
        for (int it = 0; it < 4; ++it) {
          float4 y0 = *(const float4*)(a1 + it * 8);
          float4 y1 = *(const float4*)(a1 + it * 8 + 4);
          x0[it].x += y0.x; x0[it].y += y0.y; x0[it].z += y0.z; x0[it].w += y0.w;
          x1[it].x += y1.x; x1[it].y += y1.y; x1[it].z += y1.z; x1[it].w += y1.w;
        }
      }
#pragma unroll
      for (int it = 0; it < 4; ++it) {
        short8 v;
        v[0] = (short)f2bf(x0[it].x); v[1] = (short)f2bf(x0[it].y);
        v[2] = (short)f2bf(x0[it].z); v[3] = (short)f2bf(x0[it].w);
        v[4] = (short)f2bf(x1[it].x); v[5] = (short)f2bf(x1[it].y);
        v[6] = (short)f2bf(x1[it].z); v[7] = (short)f2bf(x1[it].w);
        *(short8*)&As[r][half * 32 + it * 8] = v;
      }
    }
    // ---- stage B: bf16 global -> LDS ----
    {
      short8 vb[4];
#pragma unroll
      for (int it = 0; it < 4; ++it) {
        int idx = it * 256 + t; int n = idx >> 3, k8 = (idx & 7) * 8;
        vb[it] = *(const short8*)&Bt[(size_t)(tn * 128 + n) * 512 + kt * 64 + k8];
      }
#pragma unroll
      for (int it = 0; it < 4; ++it) {
        int idx = it * 256 + t; int n = idx >> 3, k8 = (idx & 7) * 8;
        *(short8*)&Bs[n][k8] = vb[it];
      }
    }
    __syncthreads();
    // ---- MFMA ----
#pragma unroll
    for (int kk = 0; kk < 2; ++kk) {
      short8 af[4], bf[4];
#pragma unroll
      for (int m = 0; m < 4; ++m) af[m] = *(const short8*)&As[wr * 64 + m * 16 + lr][kk * 32 + lg * 8];
#pragma unroll
      for (int n = 0; n < 4; ++n) bf[n] = *(const short8*)&Bs[wc * 64 + n * 16 + lr][kk * 32 + lg * 8];
#pragma unroll
      for (int m = 0; m < 4; ++m)
#pragma unroll
        for (int n = 0; n < 4; ++n)
          acc[m][n] = __builtin_amdgcn_mfma_f32_16x16x32_bf16(af[m], bf[n], acc[m][n], 0, 0, 0);
    }
  }

  // ---- epilogue ----
  const int c_base = tn * 128 + wc * 64;
  const int r_base = tm * 128 + wr * 64;
#pragma unroll
  for (int n = 0; n < 4; ++n) {
    const int col = c_base + n * 16 + lr;
    const float bs = bias[col];
#pragma unroll
    for (int m = 0; m < 4; ++m) {
      const int row = r_base + m * 16 + lg * 4;
      if (MODE == 1) {
#pragma unroll
        for (int j = 0; j < 4; ++j)
          Out[(size_t)(row + j) * 512 + col] = f2bf(acc[m][n][j] + bs);
      } else {
        const int b = row >> 12, nl = row & 4095;  // tile rows never cross a batch (4096 % 128 == 0)
        us4 v;
#pragma unroll
        for (int j = 0; j < 4; ++j) {
          float f = acc[m][n][j] + bs;
          if (MODE == 0) f = __expf(f);
          v[j] = f2bf(f);
        }
        *(us4*)&Out[((size_t)(b * 512 + col)) * 4096 + nl] = v;
      }
    }
  }
}

// ---------------------------------------------------------------------------
// In-place row softmax over 64 channels per (token, head). One wave per group.
__global__ void qsoftmax(unsigned short* __restrict__ Qp) {
  const int t = threadIdx.x, l = t & 63, w = t >> 6;
  const int gw = blockIdx.x * 4 + w;  // 0..4095
  for (int i = 0; i < 64; ++i) {
    const int g = gw * 64 + i;        // 0..262143
    const int m = g >> 3, h = g & 7;
    const size_t addr = (size_t)m * 512 + h * 64 + l;
    float x = bf2f(Qp[addr]);
    float mx = x;
#pragma unroll
    for (int o = 32; o; o >>= 1) mx = fmaxf(mx, __shfl_xor(mx, o));
    float e = __expf(x - mx);
    float s = e;
#pragma unroll
    for (int o = 32; o; o >>= 1) s += __shfl_xor(s, o);
    Qp[addr] = f2bf(e / s);
  }
}

// ---------------------------------------------------------------------------
// S[b*512+k] = sum over 4096 tokens of KeT row (key-softmax denominator)
__global__ void ssum(const unsigned short* __restrict__ KeT, float* __restrict__ S) {
  const int t = threadIdx.x;
  const int row = blockIdx.x;
  const unsigned short* p = KeT + (size_t)row * 4096 + t * 16;
  float s = 0.f;
#pragma unroll
  for (int q = 0; q < 2; ++q) {
    short8 v = *(const short8*)(p + q * 8);
#pragma unroll
    for (int j = 0; j < 8; ++j) s += bf2f((unsigned short)v[j]);
  }
#pragma unroll
  for (int o = 32; o; o >>= 1) s += __shfl_xor(s, o);
  __shared__ float ls[4];
  if ((t & 63) == 0) ls[t >> 6] = s;
  __syncthreads();
  if (t == 0) S[row] = ls[0] + ls[1] + ls[2] + ls[3];
}

// ---------------------------------------------------------------------------
// Partial context: D[v][k] = sum_tok VT[v][tok] * KeT[k][tok] over a 1024-token chunk.
// Register-fragment MFMA straight from global (both operands token-contiguous).
__global__ void context_partial(const unsigned short* __restrict__ KeT,
                                const unsigned short* __restrict__ VT,
                                float* __restrict__ cp) {
  const int t = threadIdx.x, l = t & 63, w = t >> 6;
  const int lr = l & 15, lg = l >> 4;
  const int ch = blockIdx.x, h = blockIdx.y, b = blockIdx.z;
  const unsigned short* Kp = KeT + ((size_t)b * 512 + h * 64) * 4096;
  const unsigned short* Vp = VT + ((size_t)b * 512 + h * 64) * 4096;
  const int tok_w = ch * 1024 + w * 256;
  f32x4 acc[4][4] = {};
  for (int s = 0; s < 8; ++s) {
    const int tok = tok_w + s * 32 + lg * 8;
    short8 a[4], kf[4];
#pragma unroll
    for (int m = 0; m < 4; ++m) a[m] = *(const short8*)&Vp[(size_t)(m * 16 + lr) * 4096 + tok];
#pragma unroll
    for (int n = 0; n < 4; ++n) kf[n] = *(const short8*)&Kp[(size_t)(n * 16 + lr) * 4096 + tok];
#pragma unroll
    for (int m = 0; m < 4; ++m)
#pragma unroll
      for (int n = 0; n < 4; ++n)
        acc[m][n] = __builtin_amdgcn_mfma_f32_16x16x32_bf16(a[m], kf[n], acc[m][n], 0, 0, 0);
  }
  // cross-wave reduce via LDS
  __shared__ float red[4][64][64];
#pragma unroll
  for (int m = 0; m < 4; ++m)
#pragma unroll
    for (int n = 0; n < 4; ++n)
#pragma unroll
      for (int j = 0; j < 4; ++j)
        red[w][m * 16 + lg * 4 + j][n * 16 + lr] = acc[m][n][j];
  __syncthreads();
  const int blk = (b * 8 + h) * 4 + ch;
  float* o = cp + (size_t)blk * 4096;
  for (int i = 0; i < 16; ++i) {
    int e = i * 256 + t;
    int v = e >> 6, k = e & 63;
    o[e] = red[0][v][k] + red[1][v][k] + red[2][v][k] + red[3][v][k];
  }
}

// Reduce 4 chunk-partials, normalize by S, store transposed: ctxN[bh][k][v] (bf16)
__global__ void ctx_reduce(const float* __restrict__ cp, const float* __restrict__ S,
                           unsigned short* __restrict__ ctxN) {
  const int bh = blockIdx.x, t = threadIdx.x;
  const float* p = cp + (size_t)bh * 4 * 4096;
  for (int i = 0; i < 16; ++i) {
    int e = i * 256 + t;
    float vsum = p[e] + p[4096 + e] + p[8192 + e] + p[12288 + e];
    int v = e >> 6, k = e & 63;
    ctxN[(size_t)bh * 4096 + k * 64 + v] = f2bf(vsum / S[bh * 64 + k]);
  }
}

// ---------------------------------------------------------------------------
// M[b][c][h*64+k] = sum_v ctxN[b,h][k][v] * Wr[h*64+v][c]   (stored transposed for final GEMM)
__global__ void ctx_mm(const unsigned short* __restrict__ ctxN, const unsigned short* __restrict__ Wrt,
                       unsigned short* __restrict__ MT) {
  const int t = threadIdx.x, l = t & 63, w = t >> 6;
  const int lr = l & 15, lg = l >> 4;
  const int h = blockIdx.x, b = blockIdx.y;
  const unsigned short* Ap = ctxN + (size_t)(b * 8 + h) * 4096;
  f32x4 acc[4][8] = {};
  const int c0 = w * 128;
#pragma unroll
  for (int kk = 0; kk < 2; ++kk) {
    const int vb = kk * 32 + lg * 8;
    short8 a[4], bfr[8];
#pragma unroll
    for (int m = 0; m < 4; ++m) a[m] = *(const short8*)&Ap[(m * 16 + lr) * 64 + vb];
#pragma unroll
    for (int n = 0; n < 8; ++n) bfr[n] = *(const short8*)&Wrt[(size_t)(c0 + n * 16 + lr) * 512 + h * 64 + vb];
#pragma unroll
    for (int m = 0; m < 4; ++m)
#pragma unroll
      for (int n = 0; n < 8; ++n)
        acc[m][n] = __builtin_amdgcn_mfma_f32_16x16x32_bf16(a[m], bfr[n], acc[m][n], 0, 0, 0);
  }
#pragma unroll
  for (int n = 0; n < 8; ++n) {
    const int c = c0 + n * 16 + lr;
#pragma unroll
    for (int m = 0; m < 4; ++m) {
      const int k = m * 16 + lg * 4;
      us4 v;
#pragma unroll
      for (int j = 0; j < 4; ++j) v[j] = f2bf(acc[m][n][j]);
      *(us4*)&MT[((size_t)b * 512 + c) * 512 + h * 64 + k] = v;
    }
  }
}

// ---------------------------------------------------------------------------
// Final GEMM: out[tok][c] = sum_j Qs[tok][j] * MT[b][c][j] + br[c]   (fp32 out)
__global__ void gemm_final(const unsigned short* __restrict__ Qs, const unsigned short* __restrict__ MT,
                           const float* __restrict__ br, float* __restrict__ out) {
  __shared__ __align__(16) unsigned short As[128][64];
  __shared__ __align__(16) unsigned short Bs[128][64];
  const int t = threadIdx.x, l = t & 63, w = t >> 6;
  const int lr = l & 15, lg = l >> 4;
  const int wr = w >> 1, wc = w & 1;
  const int tn = blockIdx.x, tm = blockIdx.y;
  const unsigned short* Bt = MT + (size_t)(tm >> 5) * 512 * 512;  // batch = tm/32
  f32x4 acc[4][4] = {};
  for (int kt = 0; kt < 8; ++kt) {
    if (kt) __syncthreads();
    {
      short8 va[4], vb[4];
#pragma unroll
      for (int it = 0; it < 4; ++it) {
        int idx = it * 256 + t; int rr = idx >> 3, k8 = (idx & 7) * 8;
        va[it] = *(const short8*)&Qs[(size_t)(tm * 128 + rr) * 512 + kt * 64 + k8];
        vb[it] = *(const short8*)&Bt[(size_t)(tn * 128 + rr) * 512 + kt * 64 + k8];
      }
#pragma unroll
      for (int it = 0; it < 4; ++it) {
        int idx = it * 256 + t; int rr = idx >> 3, k8 = (idx & 7) * 8;
        *(short8*)&As[rr][k8] = va[it];
        *(short8*)&Bs[rr][k8] = vb[it];
      }
    }
    __syncthreads();
#pragma unroll
    for (int kk = 0; kk < 2; ++kk) {
      short8 af[4], bf[4];
#pragma unroll
      for (int m = 0; m < 4; ++m) af[m] = *(const short8*)&As[wr * 64 + m * 16 + lr][kk * 32 + lg * 8];
#pragma unroll
      for (int n = 0; n < 4; ++n) bf[n] = *(const short8*)&Bs[wc * 64 + n * 16 + lr][kk * 32 + lg * 8];
#pragma unroll
      for (int m = 0; m < 4; ++m)
#pragma unroll
        for (int n = 0; n < 4; ++n)
          acc[m][n] = __builtin_amdgcn_mfma_f32_16x16x32_bf16(af[m], bf[n], acc[m][n], 0, 0, 0);
    }
  }
  const int c_base = tn * 128 + wc * 64;
  const int r_base = tm * 128 + wr * 64;
#pragma unroll
  for (int n = 0; n < 4; ++n) {
    const int col = c_base + n * 16 + lr;
    const float bs = br[col];
#pragma unroll
    for (int m = 0; m < 4; ++m) {
      const int row = r_base + m * 16 + lg * 4;
#pragma unroll
      for (int j = 0; j < 4; ++j)
        out[(size_t)(row + j) * 512 + col] = acc[m][n][j] + bs;
    }
  }
}

// ---------------------------------------------------------------------------
extern "C" void kernel_launch(void* const* d_in, const int* in_sizes, int n_in,
                              void* d_out, int out_size, void* d_ws, size_t ws_size,
                              hipStream_t stream) {
  (void)in_sizes; (void)n_in; (void)out_size; (void)ws_size;
  const float* x  = (const float*)d_in[0];
  const float* y  = (const float*)d_in[1];
  const float* Wk = (const float*)d_in[2];
  const float* bk = (const float*)d_in[3];
  const float* Wq = (const float*)d_in[4];
  const float* bq = (const float*)d_in[5];
  const float* Wv = (const float*)d_in[6];
  const float* bv = (const float*)d_in[7];
  const float* Wr = (const float*)d_in[8];
  const float* br = (const float*)d_in[9];
  float* out = (float*)d_out;

  char* ws = (char*)d_ws;
  unsigned short* Wt   = (unsigned short*)(ws + 0);            //  2 MB: 4x [512][512] bf16 (transposed)
  unsigned short* KeT  = (unsigned short*)(ws + 2097152);      // 32 MB: [B][512][4096] bf16 (exp'd keys, transposed)
  unsigned short* VT   = (unsigned short*)(ws + 35651584);     // 32 MB: [B][512][4096] bf16 (values, transposed)
  unsigned short* Qp   = (unsigned short*)(ws + 69206016);     // 32 MB: [32768][512] bf16 (queries, softmaxed in-place)
  float* S             = (float*)(ws + 102760448);             // 16 KB: key-softmax denominators
  float* cp            = (float*)(ws + 102776832);             //  4 MB: context partials
  unsigned short* ctxN = (unsigned short*)(ws + 106971136);    // .5 MB: normalized context [bh][k][v]
  unsigned short* MT   = (unsigned short*)(ws + 107495424);    //  4 MB: fused ctx@Wr, transposed [b][c][j]

  prep_w<<<dim3(8, 8, 4), 256, 0, stream>>>(Wk, Wq, Wv, Wr, Wt);
  gemm_proj<0><<<dim3(4, 256), 256, 0, stream>>>(x, y, Wt, bk, KeT);
  gemm_proj<2><<<dim3(4, 256), 256, 0, stream>>>(x, nullptr, Wt + 2 * 262144, bv, VT);
  gemm_proj<1><<<dim3(4, 256), 256, 0, stream>>>(y, nullptr, Wt + 262144, bq, Qp);
  qsoftmax<<<1024, 256, 0, stream>>>(Qp);
  ssum<<<4096, 256, 0, stream>>>(KeT, S);
  context_partial<<<dim3(4, 8, 8), 256, 0, stream>>>(KeT, VT, cp);
  ctx_reduce<<<64, 256, 0, stream>>>(cp, S, ctxN);
  ctx_mm<<<dim3(8, 8), 256, 0, stream>>>(ctxN, Wt + 3 * 262144, MT);
  gemm_final<<<dim3(4, 256), 256, 0, stream>>>(Qp, MT, br, out);
}